// Round 5
// baseline (641.247 us; speedup 1.0000x reference)
//
#include <hip/hip_runtime.h>
#include <stdint.h>

#define MQ 256
#define NB 50000
#define KD 2048
#define BN 64
#define BK 64
#define KT (KD / BK)
#define NBLK ((NB + BN - 1) / BN)  // 782

typedef __attribute__((ext_vector_type(8))) short bf16x8;
typedef __attribute__((ext_vector_type(4))) float f32x4;

__device__ __forceinline__ unsigned int pack_bf16(float a, float b) {
  unsigned int ua = __float_as_uint(a);
  ua += 0x7fffu + ((ua >> 16) & 1u);
  unsigned int ub = __float_as_uint(b);
  ub += 0x7fffu + ((ub >> 16) & 1u);
  return (ua >> 16) | (ub & 0xffff0000u);
}

// order-preserving float<->uint map (total order, works for negatives)
__device__ __forceinline__ unsigned int ordf(float f) {
  unsigned int u = __float_as_uint(f);
  return (u & 0x80000000u) ? ~u : (u | 0x80000000u);
}
__device__ __forceinline__ float deordf(unsigned int e) {
  unsigned int u = (e & 0x80000000u) ? (e ^ 0x80000000u) : ~e;
  return __uint_as_float(u);
}

__device__ __forceinline__ float wave_sum(float v) {
#pragma unroll
  for (int o = 32; o > 0; o >>= 1) v += __shfl_down(v, o, 64);
  return v;
}

// ---------------- kernel 1: queries fp32 -> bf16 (+ q norms) ----------------
__global__ __launch_bounds__(256) void prep_q(const float* __restrict__ q,
                                              unsigned short* __restrict__ qbf,
                                              float* __restrict__ qn) {
  const int b = blockIdx.x, tid = threadIdx.x;
  const float* row = q + (size_t)b * KD;
  float4 v0 = *(const float4*)(row + tid * 8);
  float4 v1 = *(const float4*)(row + tid * 8 + 4);
  float sq = v0.x * v0.x + v0.y * v0.y + v0.z * v0.z + v0.w * v0.w +
             v1.x * v1.x + v1.y * v1.y + v1.z * v1.z + v1.w * v1.w;
  uint4 o;
  o.x = pack_bf16(v0.x, v0.y);
  o.y = pack_bf16(v0.z, v0.w);
  o.z = pack_bf16(v1.x, v1.y);
  o.w = pack_bf16(v1.z, v1.w);
  *(uint4*)(qbf + (size_t)b * KD + tid * 8) = o;
  sq = wave_sum(sq);
  __shared__ float s4[4];
  if ((tid & 63) == 0) s4[tid >> 6] = sq;
  __syncthreads();
  if (tid == 0) qn[b] = sqrtf(s4[0] + s4[1] + s4[2] + s4[3]);
}

// ---------------- kernel 2: deep-pipelined bf16 MFMA GEMM ----------------
// 256(M) x 64(N) tile, BK=64, 512 threads (8 waves, M=32/wave).
// r4 post-mortem: per-kt work/wave ~400 cyc < 900 cyc HBM latency, so the
// depth-1 B prefetch stalled ~500 cyc/kt inside the barrier convoy.
// This version:
//  * B-prefetch DEPTH 2: two register banks; tile kt+4 is issued in window
//    kt and packed in window kt+2 -> ~2 kt (~800-1000 cyc) of latency
//    coverage >= 900 cyc HBM miss.
//  * Barrier every TWO K-steps over a 4-deep LDS ring (32 KB): window
//    [kt,kt+1] reads bufs kt&3,(kt+1)&3, writes (kt+2)&3,(kt+3)&3 —
//    disjoint -> one "lgkmcnt(0); s_barrier" per window (16 barriers, no
//    vmcnt drain ever; compiler's counted vmcnt at each use does the rest).
//  * A fragments register-prefetched one half-window ahead (2 banks).
//  MFMA order identical -> bit-identical scores vs r2/r4 (absmax 4.88e-4).
#define BSQ8(G0, G1)                                                       \
  (G0.x * G0.x + G0.y * G0.y + G0.z * G0.z + G0.w * G0.w + G1.x * G1.x +   \
   G1.y * G1.y + G1.z * G1.z + G1.w * G1.w)

__global__ __launch_bounds__(512, 4) void gemm_scores(
    const float* __restrict__ bank, const unsigned short* __restrict__ qbf,
    const float* __restrict__ qn, float* __restrict__ out_scores,
    unsigned long long* __restrict__ bm) {
  __shared__ alignas(16) unsigned short Bs[4][BN * BK];  // 4 x 8 KB ring
  __shared__ float qn_s[MQ];
  __shared__ float bsq_s[512];
  __shared__ float bn_s[BN];

  const int tid = threadIdx.x;  // 0..511
  const int w = tid >> 6;       // 0..7
  const int lane = tid & 63;
  const int n0 = blockIdx.x * BN;

  if (tid < MQ) qn_s[tid] = qn[tid];

  f32x4 acc[2][4] = {};

  // B staging: thread t -> row t>>3, 8-float chunk (t&7)*8 (32B/thread/kt)
  const int br = tid >> 3;
  const int bc = (tid & 7) * 8;
  const int be0 = bc ^ ((br & 7) * 8);  // swizzled bf16 slot (16B aligned)
  int brow = n0 + br;
  if (brow >= NB) brow = NB - 1;  // clamp; excluded at store
  const float* bsrc = bank + (size_t)brow * KD + bc;

  // A fragment bases: rows w*32 + {0,16} + (lane&15), col quad4*8
  const int quad4 = lane >> 4;
  const unsigned short* ab0 =
      qbf + (size_t)(w * 32 + (lane & 15)) * KD + quad4 * 8;
  const unsigned short* ab1 = ab0 + (size_t)16 * KD;

  float bsq = 0.f;
  float4 gA0, gA1, gB0, gB1;

  // ---- prologue: tiles 0,1 -> Bs[0],Bs[1]; A(0) -> bank A ----
  gA0 = *(const float4*)(bsrc);
  gA1 = *(const float4*)(bsrc + 4);
  gB0 = *(const float4*)(bsrc + BK);
  gB1 = *(const float4*)(bsrc + BK + 4);
  bsq += BSQ8(gA0, gA1);
  {
    uint4 pk;
    pk.x = pack_bf16(gA0.x, gA0.y);
    pk.y = pack_bf16(gA0.z, gA0.w);
    pk.z = pack_bf16(gA1.x, gA1.y);
    pk.w = pack_bf16(gA1.z, gA1.w);
    *(uint4*)&Bs[0][br * BK + be0] = pk;
  }
  bsq += BSQ8(gB0, gB1);
  {
    uint4 pk;
    pk.x = pack_bf16(gB0.x, gB0.y);
    pk.y = pack_bf16(gB0.z, gB0.w);
    pk.z = pack_bf16(gB1.x, gB1.y);
    pk.w = pack_bf16(gB1.z, gB1.w);
    *(uint4*)&Bs[1][br * BK + be0] = pk;
  }
  bf16x8 aA0 = *(const bf16x8*)(ab0);
  bf16x8 aA1 = *(const bf16x8*)(ab0 + 32);
  bf16x8 aA2 = *(const bf16x8*)(ab1);
  bf16x8 aA3 = *(const bf16x8*)(ab1 + 32);
  bf16x8 aB0, aB1, aB2, aB3;
  __syncthreads();  // publishes Bs[0],Bs[1]; one-time full drain is fine
  // issue tiles 2,3 AFTER the drain so they stay in flight
  gA0 = *(const float4*)(bsrc + 2 * BK);
  gA1 = *(const float4*)(bsrc + 2 * BK + 4);
  gB0 = *(const float4*)(bsrc + 3 * BK);
  gB1 = *(const float4*)(bsrc + 3 * BK + 4);

  // One half-window: MFMA(kt_) with CUR A bank; prefetch A(kt_+1) into NXT;
  // pack tile kt_+2 from G bank -> Bs[(kt_+2)&3]; issue tile kt_+4 into G.
#define HALF(KT_, CA0, CA1, CA2, CA3, NA0, NA1, NA2, NA3, G0, G1)             \
  do {                                                                        \
    const int kt_ = (KT_);                                                    \
    if (kt_ + 1 < KT) {                                                       \
      NA0 = *(const bf16x8*)(ab0 + (kt_ + 1) * BK);                           \
      NA1 = *(const bf16x8*)(ab0 + (kt_ + 1) * BK + 32);                      \
      NA2 = *(const bf16x8*)(ab1 + (kt_ + 1) * BK);                           \
      NA3 = *(const bf16x8*)(ab1 + (kt_ + 1) * BK + 32);                      \
    }                                                                         \
    const unsigned short* bsp = Bs[kt_ & 3];                                  \
    _Pragma("unroll") for (int s = 0; s < 2; ++s) {                           \
      const int kx = (s * 32 + quad4 * 8) ^ ((lane & 7) * 8);                 \
      bf16x8 bfv[4];                                                          \
      _Pragma("unroll") for (int t = 0; t < 4; ++t) bfv[t] =                  \
          *(const bf16x8*)&bsp[(t * 16 + (lane & 15)) * BK + kx];             \
      _Pragma("unroll") for (int tn = 0; tn < 4; ++tn) {                      \
        acc[0][tn] = __builtin_amdgcn_mfma_f32_16x16x32_bf16(                 \
            s ? CA1 : CA0, bfv[tn], acc[0][tn], 0, 0, 0);                     \
        acc[1][tn] = __builtin_amdgcn_mfma_f32_16x16x32_bf16(                 \
            s ? CA3 : CA2, bfv[tn], acc[1][tn], 0, 0, 0);                     \
      }                                                                       \
    }                                                                         \
    if (kt_ + 2 < KT) {                                                       \
      bsq += BSQ8(G0, G1);                                                    \
      uint4 pk;                                                               \
      pk.x = pack_bf16(G0.x, G0.y);                                           \
      pk.y = pack_bf16(G0.z, G0.w);                                           \
      pk.z = pack_bf16(G1.x, G1.y);                                           \
      pk.w = pack_bf16(G1.z, G1.w);                                           \
      *(uint4*)&Bs[(kt_ + 2) & 3][br * BK + be0] = pk;                        \
      if (kt_ + 4 < KT) {                                                     \
        const float* pp = bsrc + (kt_ + 4) * BK;                              \
        G0 = *(const float4*)(pp);                                            \
        G1 = *(const float4*)(pp + 4);                                        \
      }                                                                       \
    }                                                                         \
  } while (0)

  for (int kt = 0; kt < KT; kt += 2) {
    HALF(kt, aA0, aA1, aA2, aA3, aB0, aB1, aB2, aB3, gA0, gA1);
    HALF(kt + 1, aB0, aB1, aB2, aB3, aA0, aA1, aA2, aA3, gB0, gB1);
    if (kt + 2 < KT)
      asm volatile("s_waitcnt lgkmcnt(0)\n\ts_barrier" ::: "memory");
  }
#undef HALF

  // ---- b-norm reduce: 8 partials per row ----
  __syncthreads();
  bsq_s[tid] = bsq;
  __syncthreads();
  if (tid < BN) {
    float s = 0.f;
#pragma unroll
    for (int j = 0; j < 8; ++j) s += bsq_s[tid * 8 + j];
    bn_s[tid] = sqrtf(s);
  }
  __syncthreads();

  // ---- epilogue: scale, store, and per-(block,m) packed argmax ----
  const int quad = lane >> 4, nl = lane & 15;
#pragma unroll
  for (int tm = 0; tm < 2; ++tm) {
#pragma unroll
    for (int r = 0; r < 4; ++r) {
      const int m = w * 32 + tm * 16 + quad * 4 + r;
      const float qm = qn_s[m];
      unsigned long long best = 0ull;
#pragma unroll
      for (int tn = 0; tn < 4; ++tn) {
        const int gn = n0 + tn * 16 + nl;
        if (gn < NB) {
          const float sc =
              acc[tm][tn][r] / fmaxf(qm * bn_s[tn * 16 + nl], 1e-12f);
          out_scores[(size_t)m * NB + gn] = sc;
          const unsigned long long pk =
              ((unsigned long long)ordf(sc) << 32) | (unsigned int)gn;
          best = pk > best ? pk : best;
        }
      }
#pragma unroll
      for (int mask = 1; mask < 16; mask <<= 1) {
        const unsigned long long o = __shfl_xor(best, mask, 64);
        best = o > best ? o : best;
      }
      if (nl == 0) bm[(size_t)m * NBLK + blockIdx.x] = best;
    }
  }
}

// ---------------- kernel 3: argmax from block maxima + fp32 rescue ---------
// Global approx max from the 782 packed block maxima; blocks within
// delta=2e-3 of the max get their 64-score segment rescanned; candidates get
// exact fp32 rescoring (argmax of dot/bn is monotonic-equal to the reference
// score since qn is constant per row).
__global__ __launch_bounds__(256) void argmax_rescue(
    const unsigned long long* __restrict__ bm, const float* __restrict__ scores,
    const float* __restrict__ q, const float* __restrict__ bank,
    float* __restrict__ out_idx) {
  const int b = blockIdx.x, tid = threadIdx.x;
  const int w = tid >> 6, lane = tid & 63;
  const unsigned long long* rbm = bm + (size_t)b * NBLK;

  unsigned long long pmax = 0ull;
  for (int i = tid; i < NBLK; i += 256) {
    const unsigned long long v = rbm[i];
    pmax = v > pmax ? v : pmax;
  }
#pragma unroll
  for (int o = 32; o > 0; o >>= 1) {
    const unsigned long long v = __shfl_down(pmax, o, 64);
    pmax = v > pmax ? v : pmax;
  }
  __shared__ unsigned long long red[4];
  if (lane == 0) red[w] = pmax;
  __syncthreads();
  unsigned long long gmax = red[0];
#pragma unroll
  for (int i = 1; i < 4; ++i) gmax = red[i] > gmax ? red[i] : gmax;
  const float thr = deordf((unsigned int)(gmax >> 32)) - 2e-3f;

  __shared__ int cand[64];
  __shared__ int cnt;
  if (tid == 0) cnt = 0;
  __syncthreads();
  const float* srow = scores + (size_t)b * NB;
  for (int i = tid; i < NBLK; i += 256) {
    const float bmf = deordf((unsigned int)(rbm[i] >> 32));
    if (bmf >= thr) {  // rare (1-3 blocks): rescan its 64 scores
      const int base = i * BN;
      const int lim = min(BN, NB - base);
      for (int j = 0; j < lim; ++j) {
        if (srow[base + j] >= thr) {
          const int c = atomicAdd(&cnt, 1);
          if (c < 64) cand[c] = base + j;
        }
      }
    }
  }
  __syncthreads();
  const int nc = min(cnt, 64);

  __shared__ float dd[4], ss[4];
  float best = -1e30f;
  int bidx = 0x7fffffff;
  const float* qrow = q + (size_t)b * KD;
  for (int c = 0; c < nc; ++c) {
    const int idx = cand[c];
    const float* brow = bank + (size_t)idx * KD;
    float4 bv0 = *(const float4*)(brow + tid * 8);
    float4 bv1 = *(const float4*)(brow + tid * 8 + 4);
    float4 qv0 = *(const float4*)(qrow + tid * 8);
    float4 qv1 = *(const float4*)(qrow + tid * 8 + 4);
    float d = 0.f, s = 0.f;
    d = fmaf(qv0.x, bv0.x, d);
    s = fmaf(bv0.x, bv0.x, s);
    d = fmaf(qv0.y, bv0.y, d);
    s = fmaf(bv0.y, bv0.y, s);
    d = fmaf(qv0.z, bv0.z, d);
    s = fmaf(bv0.z, bv0.z, s);
    d = fmaf(qv0.w, bv0.w, d);
    s = fmaf(bv0.w, bv0.w, s);
    d = fmaf(qv1.x, bv1.x, d);
    s = fmaf(bv1.x, bv1.x, s);
    d = fmaf(qv1.y, bv1.y, d);
    s = fmaf(bv1.y, bv1.y, s);
    d = fmaf(qv1.z, bv1.z, d);
    s = fmaf(bv1.z, bv1.z, s);
    d = fmaf(qv1.w, bv1.w, d);
    s = fmaf(bv1.w, bv1.w, s);
    d = wave_sum(d);
    s = wave_sum(s);
    if (lane == 0) {
      dd[w] = d;
      ss[w] = s;
    }
    __syncthreads();
    const float dt = dd[0] + dd[1] + dd[2] + dd[3];
    const float st = ss[0] + ss[1] + ss[2] + ss[3];
    const float sc = dt / fmaxf(sqrtf(st), 1e-12f);
    if (sc > best || (sc == best && idx < bidx)) {
      best = sc;
      bidx = idx;
    }
    __syncthreads();
  }
  if (tid == 0) out_idx[b] = (float)bidx;
}

extern "C" void kernel_launch(void* const* d_in, const int* in_sizes, int n_in,
                              void* d_out, int out_size, void* d_ws,
                              size_t ws_size, hipStream_t stream) {
  const float* queries = (const float*)d_in[0];  // [256, 2048] fp32
  const float* bank = (const float*)d_in[1];     // [50000, 2048] fp32
  float* out = (float*)d_out;                    // [256 idx | 256*50000 scores]
  float* out_scores = out + MQ;

  char* ws = (char*)d_ws;
  unsigned short* qbf = (unsigned short*)ws;                 // 1 MB bf16 queries
  float* qn = (float*)(ws + (size_t)MQ * KD * 2);            // 1 KB q-norms
  unsigned long long* bm =
      (unsigned long long*)(ws + (size_t)MQ * KD * 2 + 2048);  // 1.6 MB maxima

  prep_q<<<MQ, 256, 0, stream>>>(queries, qbf, qn);
  gemm_scores<<<NBLK, 512, 0, stream>>>(bank, qbf, qn, out_scores, bm);
  argmax_rescue<<<MQ, 256, 0, stream>>>(bm, out_scores, queries, bank, out);
}